// Round 3
// baseline (309.172 us; speedup 1.0000x reference)
//
#include <hip/hip_runtime.h>
#include <hip/hip_cooperative_groups.h>
#include <stdint.h>

#define HD   1024
#define LD   4096
#define BATCH 4
#define KLEN 8192           // 2*L
#define LAM  0.1f
#define TAP_CAP 65536
#define NT   16             // K tiles: 1024 / 64

typedef __attribute__((ext_vector_type(8))) short short8x;
typedef __attribute__((ext_vector_type(4))) float float4x;

struct Tap { int hd; float v; };

__device__ inline unsigned short f2bf(float x) {
    union { float f; uint32_t u; } v; v.f = x;
    uint32_t u = v.u;
    u += 0x7fffu + ((u >> 16) & 1u);
    return (unsigned short)(u >> 16);
}

__device__ inline void gload16(const void* g, void* l) {
    __builtin_amdgcn_global_load_lds(
        (const __attribute__((address_space(1))) void*)g,
        (__attribute__((address_space(3))) void*)l,
        16, 0, 0);
}

__device__ inline float silu_f(float x) { return x / (1.0f + __expf(-x)); }

// ---------------------------------------------------------------------------
// ONE cooperative kernel: 256 blocks x 512 threads x 128 KiB LDS = 1 block/CU
// (exact cooperative co-residency). Replaces 3 kernels + 2 inter-kernel
// dependencies with 2 grid.sync()s. Phase math is bit-identical to the
// previous 3-kernel version (same formulas, same accumulation order).
//   Phase A: W fp32->bf16 (exact 1:1 coverage) + kernel tap scan.
//   Phase B: Vt build  silu(u*D [+ sparse conv]) -> (B*L, H) bf16, LDS-transposed.
//   Phase C: GEMM+GLU, round-2 8-phase pipeline, 2 panels/block (bid, bid+256;
//            same m0 -> A panel stays L2-hot across the pair).
// ---------------------------------------------------------------------------
#define BAR       asm volatile("s_barrier" ::: "memory")
#define WAITV2    asm volatile("s_waitcnt vmcnt(2)" ::: "memory")
#define WAITV0    asm volatile("s_waitcnt vmcnt(0)" ::: "memory")

#define STAGE(srcarr, buf, regionOff, kt) do {                                 \
    unsigned short* lb_ = smem + (buf) * 32768 + (regionOff);                  \
    gload16(srcarr[0] + (kt) * 64, lb_ + tid * 8);                             \
    gload16(srcarr[1] + (kt) * 64, lb_ + (tid + 512) * 8);                     \
} while (0)

#define LDFR(sb, rb, off, dst) do {                                            \
    _Pragma("unroll")                                                          \
    for (int _i = 0; _i < 4; _i++)                                             \
        dst[_i] = *(const short8x*)((sb) + rb[_i] + (off));                    \
} while (0)

#define MMA(afr, br, acc) do {                                                 \
    __builtin_amdgcn_s_setprio(1);                                             \
    _Pragma("unroll")                                                          \
    for (int _i = 0; _i < 4; _i++)                                             \
        _Pragma("unroll")                                                      \
        for (int _j = 0; _j < 4; _j++)                                         \
            acc[_i][_j] = __builtin_amdgcn_mfma_f32_16x16x32_bf16(             \
                afr[_i], br[_j], acc[_i][_j], 0, 0, 0);                        \
    __builtin_amdgcn_s_setprio(0);                                             \
} while (0)

__global__ __launch_bounds__(512, 2) void k_mega(
        const float* __restrict__ u, const float* __restrict__ kern,
        const float* __restrict__ Dv, const float* __restrict__ W,
        const float* __restrict__ bvec, float* __restrict__ out,
        int* __restrict__ ntaps_p, Tap* __restrict__ taps,
        unsigned short* __restrict__ Wbf, unsigned short* __restrict__ Vt) {
    __shared__ unsigned short smem[65536];       // 128 KiB (C); aliased by B
    cooperative_groups::grid_group gg = cooperative_groups::this_grid();
    int tid = threadIdx.x;
    int bid = blockIdx.x;
    int gtid = bid * 512 + tid;                  // 131072 threads

    // ================= Phase A: W -> bf16 + tap scan =======================
    {
        const float4* w4 = (const float4*)W;     // 2048*1024/4 = 524288 float4
        float4 a0 = w4[gtid * 4 + 0], a1 = w4[gtid * 4 + 1];
        float4 a2 = w4[gtid * 4 + 2], a3 = w4[gtid * 4 + 3];
        short8x o0, o1;
        o0[0] = (short)f2bf(a0.x); o0[1] = (short)f2bf(a0.y);
        o0[2] = (short)f2bf(a0.z); o0[3] = (short)f2bf(a0.w);
        o0[4] = (short)f2bf(a1.x); o0[5] = (short)f2bf(a1.y);
        o0[6] = (short)f2bf(a1.z); o0[7] = (short)f2bf(a1.w);
        o1[0] = (short)f2bf(a2.x); o1[1] = (short)f2bf(a2.y);
        o1[2] = (short)f2bf(a2.z); o1[3] = (short)f2bf(a2.w);
        o1[4] = (short)f2bf(a3.x); o1[5] = (short)f2bf(a3.y);
        o1[6] = (short)f2bf(a3.z); o1[7] = (short)f2bf(a3.w);
        *(short8x*)(Wbf + (int64_t)gtid * 16)     = o0;
        *(short8x*)(Wbf + (int64_t)gtid * 16 + 8) = o1;

        const float4* k4 = (const float4*)kern;
        int64_t total4 = (int64_t)HD * KLEN / 4; // 2097152 -> 16 iters exact
        for (int64_t i = gtid; i < total4; i += 131072) {
            float4 v = k4[i];
            float vals[4] = {v.x, v.y, v.z, v.w};
#pragma unroll
            for (int j = 0; j < 4; j++) {
                float a = fabsf(vals[j]) - LAM;
                if (a > 0.0f) {
                    int e = (int)(i * 4 + j);
                    int slot = atomicAdd(ntaps_p, 1);
                    if (slot < TAP_CAP) { taps[slot].hd = e; taps[slot].v = copysignf(a, vals[j]); }
                }
            }
        }
    }
    gg.sync();

    // ================= Phase B: Vt build (LDS transpose) ===================
    {
        float* T = (float*)smem;                 // 64*65 floats = 16.6 KiB
        int nt = *ntaps_p;
        int lq = tid & 15;
        int hh = tid >> 4;                       // 0..31
        for (int jj = 0; jj < 16; jj++) {
            int job = bid * 16 + jj;             // 4096 jobs total
            int lt = (job & 63) * 64;
            int ht = ((job >> 6) & 15) * 64;
            int b  = job >> 10;
            __syncthreads();                     // T free (prev job's reads done)
#pragma unroll
            for (int r = 0; r < 2; r++) {
                int h = hh + r * 32;
                int hg = ht + h;
                int64_t base = ((int64_t)b * HD + hg) * LD + lt + lq * 4;
                float4 v = *(const float4*)(u + base);
                float d = Dv[hg];
                v.x *= d; v.y *= d; v.z *= d; v.w *= d;
                if (nt != 0) {                   // generic sparse-conv path
                    int ncl = min(nt, TAP_CAP);
                    float acc[4] = {v.x, v.y, v.z, v.w};
                    const float* ub = u + ((int64_t)b * HD + hg) * LD;
                    for (int j = 0; j < ncl; j++) {
                        int hd = taps[j].hd;
                        if ((hd >> 13) != hg) continue;
                        int dly = hd & (KLEN - 1);
#pragma unroll
                        for (int e = 0; e < 4; e++) {
                            int t = lt + lq * 4 + e;
                            int s = t - dly;
                            if (s < 0) s += KLEN;
                            if (s < LD) acc[e] += taps[j].v * ub[s];
                        }
                    }
                    v.x = acc[0]; v.y = acc[1]; v.z = acc[2]; v.w = acc[3];
                }
                int p = h * 65 + lq * 4;
                T[p]     = silu_f(v.x);
                T[p + 1] = silu_f(v.y);
                T[p + 2] = silu_f(v.z);
                T[p + 3] = silu_f(v.w);
            }
            __syncthreads();
            int h8 = (tid & 7) * 8;
            int nb = tid >> 3;                   // 0..63
            short8x o;
#pragma unroll
            for (int j = 0; j < 8; j++) o[j] = (short)f2bf(T[(h8 + j) * 65 + nb]);
            int64_t n = (int64_t)b * LD + lt + nb;
            *(short8x*)(Vt + n * HD + ht + h8) = o;
        }
    }
    gg.sync();

    // ================= Phase C: GEMM + GLU (round-2 pipeline), 2 panels ====
    int lane = tid & 63;
    int wid  = tid >> 6;                         // 0..7
    int wm = wid >> 2, wn = wid & 3;             // 2 x 4 wave grid
    int l15 = lane & 15, quad = lane >> 4;
    int xr = l15 & 7;

    int rba[4], rbg[4], rbb[4];                  // row bases (shorts, per buf)
#pragma unroll
    for (int i = 0; i < 4; i++) {
        int ra = wm * 64 + i * 16 + l15;         // 0..127
        rba[i] = ra * 64;                        // A0 region
        rbg[i] = (128 + ra) * 64;                // A1 region
        int cb = wn * 64 + i * 16 + l15;         // 0..255
        rbb[i] = 16384 + cb * 64;                // B region (both halves)
    }
    int off0 = (quad ^ xr) * 8;                  // ks=0 swizzled slot
    int off1 = ((4 + quad) ^ xr) * 8;            // ks=1

    const unsigned short* sb0 = smem;
    const unsigned short* sb1 = smem + 32768;

    for (int pp = 0; pp < 2; pp++) {
        int flat = bid + pp * 256;               // 512 panels total, nwg%8==0
        int swz  = (flat & 7) * 64 + (flat >> 3);
        int m0   = (swz & 7) * 128;              // same m0 for pp=0/1 pair
        int n0   = (swz >> 3) * 256;

        const unsigned short* sA0[2]; const unsigned short* sA1[2];
        const unsigned short* sB0[2]; const unsigned short* sB1[2];
#pragma unroll
        for (int j = 0; j < 2; j++) {
            int c = tid + j * 512;
            int r = c >> 3, s = c & 7;
            int kg = s ^ (r & 7);
            sA0[j] = Wbf + (int64_t)(m0 + r) * HD + kg * 8;
            sA1[j] = Wbf + (int64_t)(1024 + m0 + r) * HD + kg * 8;
            sB0[j] = Vt + (int64_t)(n0 + r) * HD + kg * 8;
            sB1[j] = Vt + (int64_t)(n0 + 128 + r) * HD + kg * 8;
        }

        float4x acca[4][4], accg[4][4];
#pragma unroll
        for (int i = 0; i < 4; i++)
#pragma unroll
            for (int j = 0; j < 4; j++) {
                acca[i][j] = (float4x){0.f, 0.f, 0.f, 0.f};
                accg[i][j] = (float4x){0.f, 0.f, 0.f, 0.f};
            }

        short8x fr[4], b0r[4], b1r[4];

        __syncthreads();                         // LDS free of prior panel reads
        // prologue: tile0 full -> buf0, A0(tile1) -> buf1 (10 loads; allow 2)
        STAGE(sA0, 0, 0, 0); STAGE(sA1, 0, 8192, 0);
        STAGE(sB0, 0, 16384, 0); STAGE(sB1, 0, 24576, 0);
        STAGE(sA0, 1, 0, 1);
        WAITV2; BAR;

        for (int i = 0; i < 7; i++) {
            int t1 = 2 * i + 1, tn0 = 2 * i + 2, tn1 = 2 * i + 3;
            // P1: g/ks0 (buf0) ; stage A1(t1),B0(t1)
            LDFR(sb0, rbg, off0, fr); LDFR(sb0, rbb, off0, b0r);
            STAGE(sA1, 1, 8192, t1); STAGE(sB0, 1, 16384, t1);
            BAR; MMA(fr, b0r, accg); BAR;
            // P2: g/ks1 ; stage B1(t1)
            LDFR(sb0, rbg, off1, fr); LDFR(sb0, rbb, off1, b1r);
            STAGE(sB1, 1, 24576, t1);
            BAR; MMA(fr, b1r, accg); BAR;
            // P3: a/ks0 (reuse b0r) ; stage A1(tn0)
            LDFR(sb0, rba, off0, fr);
            STAGE(sA1, 0, 8192, tn0);
            BAR; MMA(fr, b0r, acca); BAR;
            // P4: a/ks1 (reuse b1r) ; vmcnt: t1's A1/B0/B1 landed (allow P3)
            LDFR(sb0, rba, off1, fr);
            WAITV2;
            BAR; MMA(fr, b1r, acca); BAR;
            // P5: a/ks0 (buf1) ; stage A0(tn0)
            LDFR(sb1, rba, off0, fr); LDFR(sb1, rbb, off0, b0r);
            STAGE(sA0, 0, 0, tn0);
            BAR; MMA(fr, b0r, acca); BAR;
            // P6: a/ks1 ; stage B0(tn0),B1(tn0)
            LDFR(sb1, rba, off1, fr); LDFR(sb1, rbb, off1, b1r);
            STAGE(sB0, 0, 16384, tn0); STAGE(sB1, 0, 24576, tn0);
            BAR; MMA(fr, b1r, acca); BAR;
            // P7: g/ks0 (reuse b0r) ; stage A0(tn1)
            LDFR(sb1, rbg, off0, fr);
            STAGE(sA0, 1, 0, tn1);
            BAR; MMA(fr, b0r, accg); BAR;
            // P8: g/ks1 (reuse b1r) ; vmcnt: tn0's A1/A0/B landed (allow P7)
            LDFR(sb1, rbg, off1, fr);
            WAITV2;
            BAR; MMA(fr, b1r, accg); BAR;
        }
        // tail (tiles 14,15): carryover staging of tile 15 only
        {
            LDFR(sb0, rbg, off0, fr); LDFR(sb0, rbb, off0, b0r);
            STAGE(sA1, 1, 8192, 15); STAGE(sB0, 1, 16384, 15);
            BAR; MMA(fr, b0r, accg); BAR;
            LDFR(sb0, rbg, off1, fr); LDFR(sb0, rbb, off1, b1r);
            STAGE(sB1, 1, 24576, 15);
            BAR; MMA(fr, b1r, accg); BAR;
            LDFR(sb0, rba, off0, fr);
            BAR; MMA(fr, b0r, acca); BAR;
            LDFR(sb0, rba, off1, fr);
            WAITV0;
            BAR; MMA(fr, b1r, acca); BAR;
            LDFR(sb1, rba, off0, fr); LDFR(sb1, rbb, off0, b0r);
            BAR; MMA(fr, b0r, acca); BAR;
            LDFR(sb1, rba, off1, fr); LDFR(sb1, rbb, off1, b1r);
            BAR; MMA(fr, b1r, acca); BAR;
            LDFR(sb1, rbg, off0, fr);
            BAR; MMA(fr, b0r, accg); BAR;
            LDFR(sb1, rbg, off1, fr);
            MMA(fr, b1r, accg);
        }

        // epilogue: out[b,h,l] = (a + b_a) * sigmoid(g + b_g)
        int b = n0 >> 12;
#pragma unroll
        for (int i = 0; i < 4; i++) {
            int h = m0 + wm * 64 + i * 16 + quad * 4;
            float ba[4], bg[4];
#pragma unroll
            for (int r = 0; r < 4; r++) { ba[r] = bvec[h + r]; bg[r] = bvec[1024 + h + r]; }
#pragma unroll
            for (int j = 0; j < 4; j++) {
                int n = n0 + wn * 64 + j * 16 + l15;
                int l = n & (LD - 1);
                float* op = out + ((int64_t)b * HD + h) * LD + l;
#pragma unroll
                for (int r = 0; r < 4; r++) {
                    float av = acca[i][j][r] + ba[r];
                    float gv = accg[i][j][r] + bg[r];
                    op[(int64_t)r * LD] = av / (1.0f + __expf(-gv));
                }
            }
        }
    }
}

extern "C" void kernel_launch(void* const* d_in, const int* in_sizes, int n_in,
                              void* d_out, int out_size, void* d_ws, size_t ws_size,
                              hipStream_t stream) {
    const float* u    = (const float*)d_in[0];   // (4,1024,4096)
    const float* kern = (const float*)d_in[1];   // (1,1024,8192)
    const float* Dv   = (const float*)d_in[2];   // (1,1024)
    const float* W    = (const float*)d_in[3];   // (2048,1024)
    const float* bv   = (const float*)d_in[4];   // (2048,)
    float* out = (float*)d_out;                  // (4,1024,4096)

    char* ws = (char*)d_ws;
    int* ntaps = (int*)ws;                                   // [0,256)
    Tap* taps  = (Tap*)(ws + 256);                           // 512 KiB cap
    unsigned short* Wbf = (unsigned short*)(ws + (1 << 20)); // 4 MiB
    unsigned short* Vt  = (unsigned short*)(ws + (8 << 20)); // 32 MiB

    hipMemsetAsync(ntaps, 0, 256, stream);

    void* args[] = { (void*)&u, (void*)&kern, (void*)&Dv, (void*)&W, (void*)&bv,
                     (void*)&out, (void*)&ntaps, (void*)&taps, (void*)&Wbf, (void*)&Vt };
    hipLaunchCooperativeKernel((void*)k_mega, dim3(256), dim3(512), args, 0, stream);
}

// Round 5
// 224.736 us; speedup vs baseline: 1.3757x; 1.3757x over previous
//
#include <hip/hip_runtime.h>
#include <stdint.h>

#define HD   1024
#define LD   4096
#define BATCH 4
#define KLEN 8192           // 2*L
#define LAM  0.1f
#define TAP_CAP 65536
#define NT   16             // K tiles: 1024 / 64

typedef __attribute__((ext_vector_type(8))) short short8x;
typedef __attribute__((ext_vector_type(4))) float float4x;

struct Tap { int hd; float v; };

__device__ inline unsigned short f2bf(float x) {
    union { float f; uint32_t u; } v; v.f = x;
    uint32_t u = v.u;
    u += 0x7fffu + ((u >> 16) & 1u);
    return (unsigned short)(u >> 16);
}

__device__ inline void gload16(const void* g, void* l) {
    __builtin_amdgcn_global_load_lds(
        (const __attribute__((address_space(1))) void*)g,
        (__attribute__((address_space(3))) void*)l,
        16, 0, 0);
}

__device__ inline float silu_f(float x) { return x / (1.0f + __expf(-x)); }

// ---------------------------------------------------------------------------
// k_pv: three independent jobs fused as disjoint block ranges (no ordering
// between them -> their memory streams overlap in one launch):
//   bid <  1024: W fp32->bf16
//   bid <  3072: kernel tap scan (+ per-64h-group tap counters for k_fix)
//   bid >= 3072: Vt build, TAPLESS path: silu(u*D) -> (B*L, H) bf16.
// Tap corrections (rare; zero on bench data) are applied by k_fix afterward.
// ---------------------------------------------------------------------------
__global__ __launch_bounds__(256) void k_pv(const float* __restrict__ u,
                                            const float* __restrict__ kern,
                                            const float* __restrict__ Dv,
                                            const float* __restrict__ W,
                                            int* __restrict__ ntaps,
                                            int* __restrict__ cnt64,
                                            Tap* __restrict__ taps,
                                            unsigned short* __restrict__ Wbf,
                                            unsigned short* __restrict__ Vt) {
    __shared__ float T[64 * 65];                 // used by vt blocks only
    int tid = threadIdx.x;
    int bid = blockIdx.x;

    if (bid < 1024) {                            // ---- W -> bf16 ----
        int i = bid * 256 + tid;
        const float4* w4 = (const float4*)W;
        float4 a = w4[i * 2], b = w4[i * 2 + 1];
        short8x o;
        o[0] = (short)f2bf(a.x); o[1] = (short)f2bf(a.y);
        o[2] = (short)f2bf(a.z); o[3] = (short)f2bf(a.w);
        o[4] = (short)f2bf(b.x); o[5] = (short)f2bf(b.y);
        o[6] = (short)f2bf(b.z); o[7] = (short)f2bf(b.w);
        *(short8x*)(Wbf + (int64_t)i * 8) = o;
        return;
    }
    if (bid < 3072) {                            // ---- kernel tap scan ----
        int bs = bid - 1024;
        const float4* k4 = (const float4*)kern;
        int64_t total4 = (int64_t)HD * KLEN / 4;
        int64_t stride = (int64_t)2048 * 256;
        for (int64_t i = (int64_t)bs * 256 + tid; i < total4; i += stride) {
            float4 v = k4[i];
            float vals[4] = {v.x, v.y, v.z, v.w};
#pragma unroll
            for (int j = 0; j < 4; j++) {
                float a = fabsf(vals[j]) - LAM;
                if (a > 0.0f) {
                    int e = (int)(i * 4 + j);
                    int slot = atomicAdd(ntaps, 1);
                    if (slot < TAP_CAP) { taps[slot].hd = e; taps[slot].v = copysignf(a, vals[j]); }
                    atomicAdd(&cnt64[e >> 19], 1);   // h-group = (e>>13)>>6
                }
            }
        }
        return;
    }
    // ---- Vt build, tapless ----
    int job = bid - 3072;                        // 4096 jobs
    int lt = (job & 63) * 64;
    int ht = ((job >> 6) & 15) * 64;
    int b  = job >> 10;
    int lq = tid & 15;
    int hh = tid >> 4;
#pragma unroll
    for (int r = 0; r < 4; r++) {
        int h = hh + r * 16;
        int hg = ht + h;
        int64_t base = ((int64_t)b * HD + hg) * LD + lt + lq * 4;
        float4 v = *(const float4*)(u + base);
        float d = Dv[hg];
        int p = h * 65 + lq * 4;
        T[p]     = silu_f(v.x * d);
        T[p + 1] = silu_f(v.y * d);
        T[p + 2] = silu_f(v.z * d);
        T[p + 3] = silu_f(v.w * d);
    }
    __syncthreads();
    int h8 = (tid & 7) * 8;
    int nb = tid >> 3;
#pragma unroll
    for (int p = 0; p < 2; p++) {
        int nl = nb + p * 32;
        short8x o;
#pragma unroll
        for (int j = 0; j < 8; j++) o[j] = (short)f2bf(T[(h8 + j) * 65 + nl]);
        int64_t n = (int64_t)b * LD + lt + nl;
        *(short8x*)(Vt + n * HD + ht + h8) = o;
    }
}

// ---------------------------------------------------------------------------
// k_fix: recompute Vt tiles for h-groups that have taps (full conv path,
// arithmetic identical to the original fused k_vt). Early-exits on the
// per-group counter -> ~0 cost when no taps (bench data).
// ---------------------------------------------------------------------------
__global__ __launch_bounds__(256) void k_fix(const float* __restrict__ u,
                                             const float* __restrict__ Dv,
                                             const int* __restrict__ ntaps_p,
                                             const int* __restrict__ cnt64,
                                             const Tap* __restrict__ taps,
                                             unsigned short* __restrict__ Vt) {
    __shared__ float T[64 * 65];
    int g = blockIdx.x;
    if (cnt64[g] == 0) return;
    int nt = min(*ntaps_p, TAP_CAP);
    int ht = g * 64;
    int lt = blockIdx.y * 64;
    int b  = blockIdx.z;
    int tid = threadIdx.x;
    int lq = tid & 15;
    int hh = tid >> 4;
#pragma unroll
    for (int r = 0; r < 4; r++) {
        int h = hh + r * 16;
        int hg = ht + h;
        int64_t base = ((int64_t)b * HD + hg) * LD + lt + lq * 4;
        float4 v = *(const float4*)(u + base);
        float d = Dv[hg];
        float acc[4] = {v.x * d, v.y * d, v.z * d, v.w * d};
        const float* ub = u + ((int64_t)b * HD + hg) * LD;
        for (int j = 0; j < nt; j++) {
            int hd = taps[j].hd;
            if ((hd >> 13) != hg) continue;
            int dly = hd & (KLEN - 1);
#pragma unroll
            for (int e = 0; e < 4; e++) {
                int t = lt + lq * 4 + e;
                int s = t - dly;
                if (s < 0) s += KLEN;
                if (s < LD) acc[e] += taps[j].v * ub[s];
            }
        }
        int p = h * 65 + lq * 4;
        T[p]     = silu_f(acc[0]);
        T[p + 1] = silu_f(acc[1]);
        T[p + 2] = silu_f(acc[2]);
        T[p + 3] = silu_f(acc[3]);
    }
    __syncthreads();
    int h8 = (tid & 7) * 8;
    int nb = tid >> 3;
#pragma unroll
    for (int p = 0; p < 2; p++) {
        int nl = nb + p * 32;
        short8x o;
#pragma unroll
        for (int j = 0; j < 8; j++) o[j] = (short)f2bf(T[(h8 + j) * 65 + nl]);
        int64_t n = (int64_t)b * LD + lt + nl;
        *(short8x*)(Vt + n * HD + ht + h8) = o;
    }
}

// ---------------- GEMM + GLU epilogue: 256x256 tile, BK=64, 4-PHASE --------
// Z = Wbf(2048x1024) * Vt^T(1024x16384); out = (z_a+b_a)*sigmoid(z_g+b_g)
// 8 waves (2m x 4n), 512 thr, LDS 128 KiB = 2 bufs x (A 256x64 + B 256x64).
// Round-2's 8 phases merged to 4 (R1-R4): per phase {8-16 ds_read_b128 ||
// 1-3 half-tile global_load_lds -> barrier -> 32 MFMA -> barrier}. Barriers
// 16 -> 8 per 2 K-tiles; interleave + counted vmcnt(2) (never 0 in steady
// state) preserved. Accumulation order per output element unchanged.
// Wait arithmetic (verified): at R2's vmcnt(2), outstanding = A0(t1)[prev R4]
// + A1,B0,B1(t1)[R1] + A1(tn0)[R2] = 10 -> leaves A1(tn0), confirms all t1.
// At R4's vmcnt(2): A1(tn0)+A0(tn0)+B0,B1(tn0)+A0(tn1) = 10 -> confirms tn0.
// Overwrite safety: every region's last LDS read is consumed by the MFMA
// cluster before the barrier that precedes its re-stage.
#define BAR       asm volatile("s_barrier" ::: "memory")
#define WAITV2    asm volatile("s_waitcnt vmcnt(2)" ::: "memory")
#define WAITV0    asm volatile("s_waitcnt vmcnt(0)" ::: "memory")

#define STAGE(srcarr, buf, regionOff, kt) do {                                 \
    unsigned short* lb_ = smem + (buf) * 32768 + (regionOff);                  \
    gload16(srcarr[0] + (kt) * 64, lb_ + tid * 8);                             \
    gload16(srcarr[1] + (kt) * 64, lb_ + (tid + 512) * 8);                     \
} while (0)

#define LDFR(sb, rb, off, dst) do {                                            \
    _Pragma("unroll")                                                          \
    for (int _i = 0; _i < 4; _i++)                                             \
        dst[_i] = *(const short8x*)((sb) + rb[_i] + (off));                    \
} while (0)

#define MMA1(afr, br, acc) do {                                                \
    _Pragma("unroll")                                                          \
    for (int _i = 0; _i < 4; _i++)                                             \
        _Pragma("unroll")                                                      \
        for (int _j = 0; _j < 4; _j++)                                         \
            acc[_i][_j] = __builtin_amdgcn_mfma_f32_16x16x32_bf16(             \
                afr[_i], br[_j], acc[_i][_j], 0, 0, 0);                        \
} while (0)

#define MMA2(f0, b0, f1, b1, acc) do {                                         \
    __builtin_amdgcn_s_setprio(1);                                             \
    MMA1(f0, b0, acc);                                                         \
    MMA1(f1, b1, acc);                                                         \
    __builtin_amdgcn_s_setprio(0);                                             \
} while (0)

__global__ __launch_bounds__(512, 2) void k_gemm(const unsigned short* __restrict__ Wbf,
                                                 const unsigned short* __restrict__ Vt,
                                                 const float* __restrict__ bvec,
                                                 float* __restrict__ out) {
    __shared__ unsigned short smem[65536];       // 128 KiB: buf b at b*32768 shorts
    int tid  = threadIdx.x;
    int flat = blockIdx.x;                       // 512 blocks, nwg%8==0
    int swz  = (flat & 7) * 64 + (flat >> 3);    // XCD-contiguous chunks of 64
    int m0   = (swz & 7) * 128;                  // 8 m-blocks
    int n0   = (swz >> 3) * 256;                 // 64 n-panels

    const unsigned short* sA0[2]; const unsigned short* sA1[2];
    const unsigned short* sB0[2]; const unsigned short* sB1[2];
#pragma unroll
    for (int j = 0; j < 2; j++) {
        int c = tid + j * 512;
        int r = c >> 3, s = c & 7;
        int kg = s ^ (r & 7);
        sA0[j] = Wbf + (int64_t)(m0 + r) * HD + kg * 8;
        sA1[j] = Wbf + (int64_t)(1024 + m0 + r) * HD + kg * 8;
        sB0[j] = Vt + (int64_t)(n0 + r) * HD + kg * 8;
        sB1[j] = Vt + (int64_t)(n0 + 128 + r) * HD + kg * 8;
    }

    int lane = tid & 63;
    int wid  = tid >> 6;                         // 0..7
    int wm = wid >> 2, wn = wid & 3;             // 2 x 4 wave grid
    int l15 = lane & 15, quad = lane >> 4;
    int xr = l15 & 7;

    int rba[4], rbg[4], rbb[4];                  // row bases (shorts, per buf)
#pragma unroll
    for (int i = 0; i < 4; i++) {
        int ra = wm * 64 + i * 16 + l15;         // 0..127
        rba[i] = ra * 64;                        // A0 region
        rbg[i] = (128 + ra) * 64;                // A1 region
        int cb = wn * 64 + i * 16 + l15;         // 0..255
        rbb[i] = 16384 + cb * 64;                // B region (both halves)
    }
    int off0 = (quad ^ xr) * 8;                  // ks=0 swizzled slot
    int off1 = ((4 + quad) ^ xr) * 8;            // ks=1

    const unsigned short* sb0 = smem;
    const unsigned short* sb1 = smem + 32768;

    float4x acca[4][4], accg[4][4];
#pragma unroll
    for (int i = 0; i < 4; i++)
#pragma unroll
        for (int j = 0; j < 4; j++) {
            acca[i][j] = (float4x){0.f, 0.f, 0.f, 0.f};
            accg[i][j] = (float4x){0.f, 0.f, 0.f, 0.f};
        }

    short8x fr[4], fr2[4], b0r[4], b1r[4];

    // prologue: tile0 full -> buf0, A0(tile1) -> buf1 (10 loads; allow last 2)
    STAGE(sA0, 0, 0, 0); STAGE(sA1, 0, 8192, 0);
    STAGE(sB0, 0, 16384, 0); STAGE(sB1, 0, 24576, 0);
    STAGE(sA0, 1, 0, 1);
    WAITV2; BAR;

    for (int i = 0; i < 7; i++) {
        int t1 = 2 * i + 1, tn0 = 2 * i + 2, tn1 = 2 * i + 3;
        // R1: tile t0 (buf0) g-rows, both ks ; stage A1,B0,B1(t1)->buf1
        LDFR(sb0, rbg, off0, fr);  LDFR(sb0, rbb, off0, b0r);
        LDFR(sb0, rbg, off1, fr2); LDFR(sb0, rbb, off1, b1r);
        STAGE(sA1, 1, 8192, t1); STAGE(sB0, 1, 16384, t1); STAGE(sB1, 1, 24576, t1);
        BAR; MMA2(fr, b0r, fr2, b1r, accg); BAR;
        // R2: t0 a-rows (B reused from regs) ; stage A1(tn0)->buf0 ; confirm t1
        LDFR(sb0, rba, off0, fr); LDFR(sb0, rba, off1, fr2);
        STAGE(sA1, 0, 8192, tn0);
        WAITV2;
        BAR; MMA2(fr, b0r, fr2, b1r, acca); BAR;
        // R3: tile t1 (buf1) a-rows ; stage A0,B0,B1(tn0)->buf0
        LDFR(sb1, rba, off0, fr);  LDFR(sb1, rbb, off0, b0r);
        LDFR(sb1, rba, off1, fr2); LDFR(sb1, rbb, off1, b1r);
        STAGE(sA0, 0, 0, tn0); STAGE(sB0, 0, 16384, tn0); STAGE(sB1, 0, 24576, tn0);
        BAR; MMA2(fr, b0r, fr2, b1r, acca); BAR;
        // R4: t1 g-rows (B reused) ; stage A0(tn1)->buf1 ; confirm tn0
        LDFR(sb1, rbg, off0, fr); LDFR(sb1, rbg, off1, fr2);
        STAGE(sA0, 1, 0, tn1);
        WAITV2;
        BAR; MMA2(fr, b0r, fr2, b1r, accg); BAR;
    }
    // tail (tiles 14,15): stage only tile 15 remainder
    {
        LDFR(sb0, rbg, off0, fr);  LDFR(sb0, rbb, off0, b0r);
        LDFR(sb0, rbg, off1, fr2); LDFR(sb0, rbb, off1, b1r);
        STAGE(sA1, 1, 8192, 15); STAGE(sB0, 1, 16384, 15); STAGE(sB1, 1, 24576, 15);
        BAR; MMA2(fr, b0r, fr2, b1r, accg); BAR;

        LDFR(sb0, rba, off0, fr); LDFR(sb0, rba, off1, fr2);
        WAITV0;                                  // all of tile 15 landed
        BAR; MMA2(fr, b0r, fr2, b1r, acca); BAR;

        LDFR(sb1, rba, off0, fr);  LDFR(sb1, rbb, off0, b0r);
        LDFR(sb1, rba, off1, fr2); LDFR(sb1, rbb, off1, b1r);
        BAR; MMA2(fr, b0r, fr2, b1r, acca); BAR;

        LDFR(sb1, rbg, off0, fr); LDFR(sb1, rbg, off1, fr2);
        MMA2(fr, b0r, fr2, b1r, accg);           // no barrier needed after
    }

    // epilogue: out[b,h,l] = (a + b_a) * sigmoid(g + b_g)
    int b = n0 >> 12;
#pragma unroll
    for (int i = 0; i < 4; i++) {
        int h = m0 + wm * 64 + i * 16 + quad * 4;
        float ba[4], bg[4];
#pragma unroll
        for (int r = 0; r < 4; r++) { ba[r] = bvec[h + r]; bg[r] = bvec[1024 + h + r]; }
#pragma unroll
        for (int j = 0; j < 4; j++) {
            int n = n0 + wn * 64 + j * 16 + l15;
            int l = n & (LD - 1);
            float* op = out + ((int64_t)b * HD + h) * LD + l;
#pragma unroll
            for (int r = 0; r < 4; r++) {
                float av = acca[i][j][r] + ba[r];
                float gv = accg[i][j][r] + bg[r];
                op[(int64_t)r * LD] = av / (1.0f + __expf(-gv));
            }
        }
    }
}

extern "C" void kernel_launch(void* const* d_in, const int* in_sizes, int n_in,
                              void* d_out, int out_size, void* d_ws, size_t ws_size,
                              hipStream_t stream) {
    const float* u    = (const float*)d_in[0];   // (4,1024,4096)
    const float* kern = (const float*)d_in[1];   // (1,1024,8192)
    const float* Dv   = (const float*)d_in[2];   // (1,1024)
    const float* W    = (const float*)d_in[3];   // (2048,1024)
    const float* bv   = (const float*)d_in[4];   // (2048,)
    float* out = (float*)d_out;                  // (4,1024,4096)

    char* ws = (char*)d_ws;
    int* ntaps = (int*)ws;                                   // [0,64)
    int* cnt64 = (int*)(ws + 64);                            // 16 ints
    Tap* taps  = (Tap*)(ws + 256);                           // 512 KiB cap
    unsigned short* Wbf = (unsigned short*)(ws + (1 << 20)); // 4 MiB
    unsigned short* Vt  = (unsigned short*)(ws + (8 << 20)); // 32 MiB

    hipMemsetAsync(ws, 0, 256, stream);
    hipLaunchKernelGGL(k_pv,   dim3(7168),        dim3(256), 0, stream,
                       u, kern, Dv, W, ntaps, cnt64, taps, Wbf, Vt);
    hipLaunchKernelGGL(k_fix,  dim3(16, 64, 4),   dim3(256), 0, stream,
                       u, Dv, ntaps, cnt64, taps, Vt);
    hipLaunchKernelGGL(k_gemm, dim3(512),         dim3(512), 0, stream, Wbf, Vt, bv, out);
}